// Round 4
// baseline (708.106 us; speedup 1.0000x reference)
//
#include <hip/hip_runtime.h>
#include <hip/hip_bf16.h>

#define PI_F 3.14159265358979323846f

typedef short  bf16x8 __attribute__((ext_vector_type(8)));
typedef unsigned short u16x8 __attribute__((ext_vector_type(8)));
typedef float  f32x4  __attribute__((ext_vector_type(4)));

// ---- ws layout (bytes) ----
#define OUT3_OFF  0                       // [3][1024][257] f32 = 3,158,016 B
#define TPACK_OFF 3158016                 // [544 tiles][64][8] bf16 = 557,056 B

static __device__ __forceinline__ unsigned short f2bf(float x) {
    unsigned int u = __float_as_uint(x);
    unsigned int r = (u + 0x7fffu + ((u >> 16) & 1u)) >> 16;   // RNE
    return (unsigned short)r;
}

// ------------------------------------------------------------------
// Kernel A: three LinearOutputStacks (unchanged)
// ------------------------------------------------------------------

__device__ __forceinline__ void block_ln(float (*buf)[256], float* mrow, float* rrow)
{
    const int tid = threadIdx.x;
    const int lane = tid & 63, wv = tid >> 6;
    for (int r = wv; r < 16; r += 4) {
        float s = 0.f, s2 = 0.f;
        #pragma unroll
        for (int j = 0; j < 4; j++) {
            float v = buf[r][lane + 64*j];
            s += v; s2 += v*v;
        }
        #pragma unroll
        for (int o = 32; o > 0; o >>= 1) {
            s  += __shfl_xor(s,  o, 64);
            s2 += __shfl_xor(s2, o, 64);
        }
        if (lane == 0) {
            float m   = s * (1.f/256.f);
            float var = s2 * (1.f/256.f) - m*m;
            mrow[r] = m;
            rrow[r] = rsqrtf(var + 1e-5f);
        }
    }
    __syncthreads();
    #pragma unroll
    for (int r = 0; r < 16; r++)
        buf[r][tid] = (buf[r][tid] - mrow[r]) * rrow[r];
    __syncthreads();
}

__device__ __forceinline__ void mm256(const float (*in)[256], const float* __restrict__ W,
                                      const float* __restrict__ bias, float (*outb)[256])
{
    const int tid = threadIdx.x;
    float acc[16];
    #pragma unroll
    for (int r = 0; r < 16; r++) acc[r] = 0.f;
    const float* Wp = W + tid;
    for (int l = 0; l < 256; l++) {
        float w = Wp[l*256];
        #pragma unroll
        for (int r = 0; r < 16; r++) acc[r] = fmaf(in[r][l], w, acc[r]);
    }
    const float bb = bias[tid];
    #pragma unroll
    for (int r = 0; r < 16; r++) {
        float v = acc[r] + bb;
        outb[r][tid] = (v >= 0.f) ? v : 0.2f*v;
    }
}

__global__ __launch_bounds__(256) void mlp_kernel(
    const float* __restrict__ latents,
    const float* __restrict__ Win,  const float* __restrict__ b_in,
    const float* __restrict__ Wh,   const float* __restrict__ b_h,
    const float* __restrict__ Wout, const float* __restrict__ b_out,
    float* __restrict__ out3)
{
    __shared__ float bufA[16][128];
    __shared__ float bufB[16][256];
    __shared__ float bufC[16][256];
    __shared__ float mrow[16], rrow[16];

    const int tid  = threadIdx.x;
    const int s    = blockIdx.y;
    const int row0 = blockIdx.x * 16;

    for (int idx = tid; idx < 16*128; idx += 256) {
        int r = idx >> 7, l = idx & 127;
        bufA[r][l] = latents[(size_t)(row0 + r)*128 + l];
    }
    __syncthreads();

    {
        float acc[16];
        #pragma unroll
        for (int r = 0; r < 16; r++) acc[r] = 0.f;
        const float* Wp = Win + (size_t)s*128*256 + tid;
        for (int l = 0; l < 128; l++) {
            float w = Wp[l*256];
            #pragma unroll
            for (int r = 0; r < 16; r++) acc[r] = fmaf(bufA[r][l], w, acc[r]);
        }
        const float bias = b_in[s*256 + tid];
        #pragma unroll
        for (int r = 0; r < 16; r++) {
            float v = acc[r] + bias;
            bufB[r][tid] = (v >= 0.f) ? v : 0.2f*v;
        }
    }
    __syncthreads();
    block_ln(bufB, mrow, rrow);

    mm256(bufB, Wh + ((size_t)s*2 + 0)*256*256, b_h + (s*2 + 0)*256, bufC);
    __syncthreads();
    block_ln(bufC, mrow, rrow);

    mm256(bufC, Wh + ((size_t)s*2 + 1)*256*256, b_h + (s*2 + 1)*256, bufB);
    __syncthreads();
    block_ln(bufB, mrow, rrow);

    for (int pass = 0; pass < 2; ++pass) {
        int n = tid + pass*256;
        if (n < 257) {
            float acc[16];
            #pragma unroll
            for (int r = 0; r < 16; r++) acc[r] = 0.f;
            const float* Wp = Wout + (size_t)s*256*257 + n;
            for (int l = 0; l < 256; l++) {
                float w = Wp[l*257];
                #pragma unroll
                for (int r = 0; r < 16; r++) acc[r] = fmaf(bufB[r][l], w, acc[r]);
            }
            float bb = b_out[s*257 + n];
            for (int r = 0; r < 16; r++)
                out3[((size_t)s*1024 + row0 + r)*257 + n] = acc[r] + bb;
        }
    }
}

// ------------------------------------------------------------------
// K1: pack iDFT basis T[k2][w] (bf16) in MFMA B-fragment order (unchanged)
// ------------------------------------------------------------------
__global__ __launch_bounds__(256) void tpack_init(unsigned short* __restrict__ tp)
{
    int g = blockIdx.x * 256 + threadIdx.x;      // 544*64 = 34816 threads exactly
    int tile = g >> 6, l = g & 63;
    int ks = tile >> 5, nt = tile & 31;
    u16x8 v;
    #pragma unroll
    for (int j = 0; j < 8; ++j) {
        int k2 = ks*32 + ((l >> 4) << 3) + j;
        int w  = nt*16 + (l & 15);
        float val = 0.f;
        if (k2 < 514) {
            int kk = k2 >> 1;
            int m  = (kk * w) & 511;
            float ang = (float)m * (PI_F / 256.f);
            float sn, cn; sincosf(ang, &sn, &cn);
            val = (k2 & 1) ? sn : cn;
        }
        v[j] = f2bf(val);
    }
    *(u16x8*)(tp + (size_t)g * 8) = v;
}

// ------------------------------------------------------------------
// K2: full-row fused scan + MFMA iDFT + Hann/OLA.
// grid 1024 (one block per row), block 320 (5 waves).
//   threads 0..255 : spectral bin k=tid (scan) + GEMM + OLA column w=tid
//   thread  256    : spectral bin 256 (scan only)
//   threads 257..271: re-zero LDS pad columns each sweep
// Two sweeps of 64 frames: scan -> abt[64][276] u32 -> MFMA (M=64,N=512,K=544)
// -> two xb passes of 32 frames -> OLA (tail carried in register across all
// 128 frames; final tail dropped = out[..., :RS] truncation).
// ------------------------------------------------------------------
__global__ __launch_bounds__(320) void synth_row(
    const float* __restrict__ out3,
    const float* __restrict__ phase0_u,
    const float* __restrict__ noise_u,
    const unsigned short* __restrict__ tpack,
    float* __restrict__ out)
{
    __shared__ __align__(16) unsigned char lds_raw[73728];
    unsigned int* abt = (unsigned int*)lds_raw;     // [64][276] u32 (70,656 B)
    float*        xb  = (float*)lds_raw;            // [512][36]  f32 (73,728 B)

    const int tid = threadIdx.x;
    const int row = blockIdx.x;
    const int b   = row >> 9;
    const int e   = row & 511;

    // ---- per-thread sequential state (k = tid, 0..256) ----
    const float inv = 0.04419417382415922f;         // 1/sqrt(512)
    float res = 0.f, dith = 0.f, pha = 0.f, mag = 0.f, gd = 0.f, cs = 0.f;
    if (tid <= 256) {
        const int k = tid;
        float ini  = out3[((size_t)0*1024 + row)*257 + k];
        float rpre = out3[((size_t)1*1024 + row)*257 + k];
        float dpre = out3[((size_t)2*1024 + row)*257 + k];
        res  = 0.5f + 0.4995f / (1.f + expf(-rpre));
        dith = 1.f / (1.f + expf(-dpre));
        pha  = (phase0_u[(size_t)row*257 + k]*2.f - 1.f) * PI_F;
        mag  = ini;
        gd   = PI_F * (float)k * (1.f/256.f);
        cs   = ((k == 0) | (k == 256) ? 1.f : 2.f) * inv;
    }

    const float* nrow = noise_u + ((size_t)b*128*512 + e)*257;
    const size_t nstride = (size_t)512*257;

    // OLA constants for w = tid (threads < 256)
    float h1 = 0.f, h2 = 0.f;
    {
        float c0 = cosf((float)tid * (PI_F/256.f));
        h1 = 0.5f - 0.5f*c0;                        // hann[tid]
        h2 = 0.5f + 0.5f*c0;                        // hann[tid+256]
    }
    float tail = 0.f;

    const int l  = tid & 63;
    const int wv = tid >> 6;
    const int4* abt4 = (const int4*)lds_raw;        // [64][69] int4
    const int4* Tp   = (const int4*)tpack;
    const int a_col  = (l >> 4);
    const int m0     = (l & 15);

    for (int sweep = 0; sweep < 2; ++sweep) {
        const int F0 = sweep * 64;

        // ---- phase 1: scan 64 frames into abt ----
        if (tid <= 256) {
            const int k = tid;
            for (int grp = 0; grp < 4; ++grp) {
                const int tb = F0 + grp*16;
                float nzb[16];
                #pragma unroll
                for (int j = 0; j < 16; ++j) {
                    int t = tb + j;
                    nzb[j] = (t >= 1) ? nrow[(size_t)t*nstride + k] : 0.5f;
                }
                #pragma unroll
                for (int j = 0; j < 16; ++j) {
                    int t = tb + j;
                    if (t >= 1) {
                        float nz = (nzb[j]*2.f - 1.f) * PI_F;
                        mag *= res;
                        pha += gd + dith*nz;
                    }
                    float sn, cn; sincosf(pha, &sn, &cn);
                    float am = cs * mag;
                    abt[(t - F0)*276 + k] =
                        (unsigned int)f2bf(am*cn) | ((unsigned int)f2bf(-am*sn) << 16);
                }
            }
        } else if (tid < 272) {
            // re-zero K-padding columns (u32 cols 257..271), clobbered by xb
            for (int f = 0; f < 64; ++f)
                abt[f*276 + tid] = 0;
        }
        __syncthreads();

        // ---- phase 2: MFMA  X[f][w] = AB^T[f][k2] * T[k2][w], M=64 ----
        f32x4 acc[4][8];
        if (tid < 256) {
            #pragma unroll
            for (int mt = 0; mt < 4; ++mt)
                #pragma unroll
                for (int nt = 0; nt < 8; ++nt)
                    acc[mt][nt] = (f32x4){0.f, 0.f, 0.f, 0.f};

            for (int ks = 0; ks < 17; ++ks) {
                int4 ai[4];
                #pragma unroll
                for (int mt = 0; mt < 4; ++mt)
                    ai[mt] = abt4[(m0 + 16*mt)*69 + ks*4 + a_col];
                const int4* tb = Tp + (size_t)(ks*32 + wv*8)*64 + l;
                #pragma unroll
                for (int nt = 0; nt < 8; ++nt) {
                    int4 bi = tb[nt*64];
                    bf16x8 B = *(bf16x8*)&bi;
                    #pragma unroll
                    for (int mt = 0; mt < 4; ++mt) {
                        bf16x8 A = *(bf16x8*)&ai[mt];
                        acc[mt][nt] = __builtin_amdgcn_mfma_f32_16x16x32_bf16(A, B, acc[mt][nt], 0, 0, 0);
                    }
                }
            }
        }
        __syncthreads();   // abt reads done; xb may now overwrite

        // ---- phase 3: two 32-frame halves: acc -> xb -> Hann+OLA ----
        for (int h = 0; h < 2; ++h) {
            if (tid < 256) {
                #pragma unroll
                for (int mt = 0; mt < 2; ++mt)
                    #pragma unroll
                    for (int nt = 0; nt < 8; ++nt) {
                        int w     = wv*128 + nt*16 + m0;
                        int fbase = mt*16 + (a_col << 2);
                        *(f32x4*)(&xb[w*36 + fbase]) = acc[2*h + mt][nt];
                    }
            }
            __syncthreads();
            if (tid < 256) {
                const f32x4* xA = (const f32x4*)&xb[tid*36];
                const f32x4* xB = (const f32x4*)&xb[(tid + 256)*36];
                float* orow = out + (size_t)row*32768 + (size_t)(F0 + 32*h)*256 + tid;
                #pragma unroll
                for (int q = 0; q < 8; ++q) {
                    f32x4 xa = xA[q];
                    f32x4 xv = xB[q];
                    #pragma unroll
                    for (int r = 0; r < 4; ++r) {
                        float v = fmaf(xa[r], h1, tail);
                        tail = xv[r] * h2;
                        orow[(q*4 + r)*256] = v;
                    }
                }
            }
            __syncthreads();   // xb reads done before next write (or next sweep's abt)
        }
    }
}

// ------------------------------------------------------------------

extern "C" void kernel_launch(void* const* d_in, const int* in_sizes, int n_in,
                              void* d_out, int out_size, void* d_ws, size_t ws_size,
                              hipStream_t stream)
{
    const float* latents  = (const float*)d_in[0];
    const float* phase0_u = (const float*)d_in[1];
    const float* noise_u  = (const float*)d_in[2];
    const float* Win      = (const float*)d_in[3];
    const float* b_in     = (const float*)d_in[4];
    const float* Wh       = (const float*)d_in[5];
    const float* b_h      = (const float*)d_in[6];
    const float* Wout     = (const float*)d_in[7];
    const float* b_out    = (const float*)d_in[8];

    unsigned char* ws = (unsigned char*)d_ws;
    float*          out3  = (float*)(ws + OUT3_OFF);
    unsigned short* tpack = (unsigned short*)(ws + TPACK_OFF);
    float*          out   = (float*)d_out;

    dim3 gA(64, 3);
    mlp_kernel<<<gA, 256, 0, stream>>>(latents, Win, b_in, Wh, b_h, Wout, b_out, out3);
    tpack_init<<<136, 256, 0, stream>>>(tpack);
    synth_row<<<1024, 320, 0, stream>>>(out3, phase0_u, noise_u, tpack, out);
}

// Round 5
// 543.370 us; speedup vs baseline: 1.3032x; 1.3032x over previous
//
#include <hip/hip_runtime.h>
#include <hip/hip_bf16.h>

#define PI_F 3.14159265358979323846f

typedef short  bf16x8 __attribute__((ext_vector_type(8)));
typedef unsigned short u16x8 __attribute__((ext_vector_type(8)));
typedef float  f32x4  __attribute__((ext_vector_type(4)));

// ---- ws layout (bytes) ----
#define OUT3_OFF  0                       // [3][1024][257] f32 = 3,158,016 B
#define TPACK_OFF 3158016                 // [512 tiles][64][8] bf16 = 524,288 B

static __device__ __forceinline__ unsigned short f2bf(float x) {
    unsigned int u = __float_as_uint(x);
    unsigned int r = (u + 0x7fffu + ((u >> 16) & 1u)) >> 16;   // RNE
    return (unsigned short)r;
}

// ------------------------------------------------------------------
// Kernel A: three LinearOutputStacks (unchanged)
// ------------------------------------------------------------------

__device__ __forceinline__ void block_ln(float (*buf)[256], float* mrow, float* rrow)
{
    const int tid = threadIdx.x;
    const int lane = tid & 63, wv = tid >> 6;
    for (int r = wv; r < 16; r += 4) {
        float s = 0.f, s2 = 0.f;
        #pragma unroll
        for (int j = 0; j < 4; j++) {
            float v = buf[r][lane + 64*j];
            s += v; s2 += v*v;
        }
        #pragma unroll
        for (int o = 32; o > 0; o >>= 1) {
            s  += __shfl_xor(s,  o, 64);
            s2 += __shfl_xor(s2, o, 64);
        }
        if (lane == 0) {
            float m   = s * (1.f/256.f);
            float var = s2 * (1.f/256.f) - m*m;
            mrow[r] = m;
            rrow[r] = rsqrtf(var + 1e-5f);
        }
    }
    __syncthreads();
    #pragma unroll
    for (int r = 0; r < 16; r++)
        buf[r][tid] = (buf[r][tid] - mrow[r]) * rrow[r];
    __syncthreads();
}

__device__ __forceinline__ void mm256(const float (*in)[256], const float* __restrict__ W,
                                      const float* __restrict__ bias, float (*outb)[256])
{
    const int tid = threadIdx.x;
    float acc[16];
    #pragma unroll
    for (int r = 0; r < 16; r++) acc[r] = 0.f;
    const float* Wp = W + tid;
    for (int l = 0; l < 256; l++) {
        float w = Wp[l*256];
        #pragma unroll
        for (int r = 0; r < 16; r++) acc[r] = fmaf(in[r][l], w, acc[r]);
    }
    const float bb = bias[tid];
    #pragma unroll
    for (int r = 0; r < 16; r++) {
        float v = acc[r] + bb;
        outb[r][tid] = (v >= 0.f) ? v : 0.2f*v;
    }
}

__global__ __launch_bounds__(256) void mlp_kernel(
    const float* __restrict__ latents,
    const float* __restrict__ Win,  const float* __restrict__ b_in,
    const float* __restrict__ Wh,   const float* __restrict__ b_h,
    const float* __restrict__ Wout, const float* __restrict__ b_out,
    float* __restrict__ out3)
{
    __shared__ float bufA[16][128];
    __shared__ float bufB[16][256];
    __shared__ float bufC[16][256];
    __shared__ float mrow[16], rrow[16];

    const int tid  = threadIdx.x;
    const int s    = blockIdx.y;
    const int row0 = blockIdx.x * 16;

    for (int idx = tid; idx < 16*128; idx += 256) {
        int r = idx >> 7, l = idx & 127;
        bufA[r][l] = latents[(size_t)(row0 + r)*128 + l];
    }
    __syncthreads();

    {
        float acc[16];
        #pragma unroll
        for (int r = 0; r < 16; r++) acc[r] = 0.f;
        const float* Wp = Win + (size_t)s*128*256 + tid;
        for (int l = 0; l < 128; l++) {
            float w = Wp[l*256];
            #pragma unroll
            for (int r = 0; r < 16; r++) acc[r] = fmaf(bufA[r][l], w, acc[r]);
        }
        const float bias = b_in[s*256 + tid];
        #pragma unroll
        for (int r = 0; r < 16; r++) {
            float v = acc[r] + bias;
            bufB[r][tid] = (v >= 0.f) ? v : 0.2f*v;
        }
    }
    __syncthreads();
    block_ln(bufB, mrow, rrow);

    mm256(bufB, Wh + ((size_t)s*2 + 0)*256*256, b_h + (s*2 + 0)*256, bufC);
    __syncthreads();
    block_ln(bufC, mrow, rrow);

    mm256(bufC, Wh + ((size_t)s*2 + 1)*256*256, b_h + (s*2 + 1)*256, bufB);
    __syncthreads();
    block_ln(bufB, mrow, rrow);

    for (int pass = 0; pass < 2; ++pass) {
        int n = tid + pass*256;
        if (n < 257) {
            float acc[16];
            #pragma unroll
            for (int r = 0; r < 16; r++) acc[r] = 0.f;
            const float* Wp = Wout + (size_t)s*256*257 + n;
            for (int l = 0; l < 256; l++) {
                float w = Wp[l*257];
                #pragma unroll
                for (int r = 0; r < 16; r++) acc[r] = fmaf(bufB[r][l], w, acc[r]);
            }
            float bb = b_out[s*257 + n];
            for (int r = 0; r < 16; r++)
                out3[((size_t)s*1024 + row0 + r)*257 + n] = acc[r] + bb;
        }
    }
}

// ------------------------------------------------------------------
// K1: pack iDFT basis T[k2][w] (bf16), MFMA B-fragment order, K=512.
//  k2 = 2k -> cos(2*pi*k*w/512), k2 = 2k+1 -> sin(2*pi*k*w/512), k = 0..255
// ------------------------------------------------------------------
__global__ __launch_bounds__(256) void tpack_init(unsigned short* __restrict__ tp)
{
    int g = blockIdx.x * 256 + threadIdx.x;      // 512*64 = 32768 threads exactly
    int tile = g >> 6, l = g & 63;
    int ks = tile >> 5, nt = tile & 31;
    u16x8 v;
    #pragma unroll
    for (int j = 0; j < 8; ++j) {
        int k2 = ks*32 + ((l >> 4) << 3) + j;    // < 512
        int w  = nt*16 + (l & 15);
        int kk = k2 >> 1;
        int m  = (kk * w) & 511;                 // exact angle reduction
        float ang = (float)m * (PI_F / 256.f);
        float sn, cn; sincosf(ang, &sn, &cn);
        v[j] = f2bf((k2 & 1) ? sn : cn);
    }
    *(u16x8*)(tp + (size_t)g * 8) = v;
}

// ------------------------------------------------------------------
// K2: full-row fused scan + MFMA iDFT + Hann/OLA.
// grid 1024 (one block per row), block 512 (8 waves), target 2 blocks/CU.
//   scan: threads 0..256 own bin k=tid; phase kept in REVOLUTIONS, hardware
//         v_sin/v_cos (D = sin/cos(S0*2pi)) after fract.
//   GEMM: K=512 (k=0..255 interleaved cos/sin); wave wv owns 64 output cols;
//         acc[4][4] (64 regs). Nyquist bin k=256 added as a256*(-1)^w in OLA.
// LDS union: abt u32[64][260] (scan/GEMM)  |  xb f32[32][516] (epilogue)
// ------------------------------------------------------------------
__global__ __launch_bounds__(512, 4) void synth_row(
    const float* __restrict__ out3,
    const float* __restrict__ phase0_u,
    const float* __restrict__ noise_u,
    const unsigned short* __restrict__ tpack,
    float* __restrict__ out)
{
    __shared__ __align__(16) unsigned char lds_raw[66560];
    __shared__ float a256s[64];
    unsigned int* abt = (unsigned int*)lds_raw;     // [64][260] u32
    float*        xbf = (float*)lds_raw;            // [32][516] f32

    const int tid = threadIdx.x;
    const int row = blockIdx.x;
    const int b   = row >> 9;
    const int e   = row & 511;

    // ---- per-thread sequential state (k = tid, 0..256), in revolutions ----
    const float inv = 0.04419417382415922f;         // 1/sqrt(512)
    float res = 0.f, dith = 0.f, pr = 0.f, mag = 0.f, gd = 0.f, cs = 0.f;
    if (tid <= 256) {
        const int k = tid;
        float ini  = out3[((size_t)0*1024 + row)*257 + k];
        float rpre = out3[((size_t)1*1024 + row)*257 + k];
        float dpre = out3[((size_t)2*1024 + row)*257 + k];
        res  = 0.5f + 0.4995f / (1.f + expf(-rpre));
        dith = 1.f / (1.f + expf(-dpre));
        pr   = phase0_u[(size_t)row*257 + k] - 0.5f;      // rev
        mag  = ini;
        gd   = (float)k * (1.f/512.f);                     // rev per frame
        cs   = ((k == 0) | (k == 256) ? 1.f : 2.f) * inv;
    }

    const float* nrow = noise_u + ((size_t)b*128*512 + e)*257;
    const size_t nstride = (size_t)512*257;

    // OLA constants for w = tid (threads < 256)
    float h1 = 0.f, h2 = 0.f;
    {
        float c0 = cosf((float)tid * (PI_F/256.f));
        h1 = 0.5f - 0.5f*c0;                        // hann[tid]
        h2 = 0.5f + 0.5f*c0;                        // hann[tid+256]
    }
    float tail = 0.f;

    const int l  = tid & 63;
    const int wv = tid >> 6;                        // 0..7: 64-col slice
    const int m0 = l & 15;
    const int ac = l >> 4;
    const int4* abt4 = (const int4*)lds_raw;        // row stride 65 int4
    const int4* Tp   = (const int4*)tpack;

    for (int sweep = 0; sweep < 2; ++sweep) {
        const int F0 = sweep * 64;

        // ---- phase 1: scan 64 frames -> abt (+ a256s) ----
        if (tid <= 256) {
            const int k = tid;
            #pragma unroll
            for (int grp = 0; grp < 4; ++grp) {
                float nzb[16];
                #pragma unroll
                for (int j = 0; j < 16; ++j) {
                    int t = F0 + grp*16 + j;
                    nzb[j] = (t >= 1) ? nrow[(size_t)t*nstride + k] : 0.5f;
                }
                #pragma unroll
                for (int j = 0; j < 16; ++j) {
                    int t = F0 + grp*16 + j;
                    if (t >= 1) {
                        mag *= res;
                        pr  += gd + dith * (nzb[j] - 0.5f);
                    }
                    float fr = pr - floorf(pr);
                    float sn = __builtin_amdgcn_sinf(fr);
                    float cn = __builtin_amdgcn_cosf(fr);
                    float am = cs * mag;
                    if (k < 256) {
                        abt[(grp*16 + j)*260 + k] =
                            (unsigned int)f2bf(am*cn) | ((unsigned int)f2bf(-am*sn) << 16);
                    } else {
                        a256s[grp*16 + j] = am * cn;   // sin(pi*w)=0: only cos term
                    }
                }
            }
        }
        __syncthreads();

        // ---- phase 2: MFMA  X[f][w] = AB^T[f][k2] * T[k2][w], M=64, K=512 ----
        f32x4 acc[4][4];
        #pragma unroll
        for (int mt = 0; mt < 4; ++mt)
            #pragma unroll
            for (int nt = 0; nt < 4; ++nt)
                acc[mt][nt] = (f32x4){0.f, 0.f, 0.f, 0.f};

        for (int ks = 0; ks < 16; ++ks) {
            int4 ai[4];
            #pragma unroll
            for (int mt = 0; mt < 4; ++mt)
                ai[mt] = abt4[(m0 + 16*mt)*65 + ks*4 + ac];
            const int4* tb = Tp + (size_t)(ks*32 + wv*4)*64 + l;
            #pragma unroll
            for (int nt = 0; nt < 4; ++nt) {
                int4 bi = tb[nt*64];
                bf16x8 B = *(bf16x8*)&bi;
                #pragma unroll
                for (int mt = 0; mt < 4; ++mt) {
                    bf16x8 A = *(bf16x8*)&ai[mt];
                    acc[mt][nt] = __builtin_amdgcn_mfma_f32_16x16x32_bf16(A, B, acc[mt][nt], 0, 0, 0);
                }
            }
        }
        __syncthreads();   // abt reads done; xbf may overwrite

        // ---- phase 3: two 32-frame halves: acc -> xb -> Hann+OLA ----
        #pragma unroll
        for (int h = 0; h < 2; ++h) {
            #pragma unroll
            for (int mt2 = 0; mt2 < 2; ++mt2) {
                int mtg = 2*h + mt2;
                #pragma unroll
                for (int nt = 0; nt < 4; ++nt) {
                    int col = (wv*4 + nt)*16 + m0;
                    #pragma unroll
                    for (int r = 0; r < 4; ++r) {
                        int f_loc = mt2*16 + ac*4 + r;
                        xbf[f_loc*516 + col] = acc[mtg][nt][r];
                    }
                }
            }
            __syncthreads();
            if (tid < 256) {
                float sgn = (tid & 1) ? -1.f : 1.f;
                float* orow = out + (size_t)row*32768 + (size_t)(F0 + h*32)*256 + tid;
                #pragma unroll
                for (int f = 0; f < 32; ++f) {
                    float s  = a256s[h*32 + f] * sgn;
                    float x1 = xbf[f*516 + tid] + s;
                    float x2 = xbf[f*516 + tid + 256] + s;
                    float v  = fmaf(x1, h1, tail);
                    tail = x2 * h2;
                    orow[f*256] = v;
                }
            }
            __syncthreads();   // xb reads done before next write / next sweep's abt
        }
    }
}

// ------------------------------------------------------------------

extern "C" void kernel_launch(void* const* d_in, const int* in_sizes, int n_in,
                              void* d_out, int out_size, void* d_ws, size_t ws_size,
                              hipStream_t stream)
{
    const float* latents  = (const float*)d_in[0];
    const float* phase0_u = (const float*)d_in[1];
    const float* noise_u  = (const float*)d_in[2];
    const float* Win      = (const float*)d_in[3];
    const float* b_in     = (const float*)d_in[4];
    const float* Wh       = (const float*)d_in[5];
    const float* b_h      = (const float*)d_in[6];
    const float* Wout     = (const float*)d_in[7];
    const float* b_out    = (const float*)d_in[8];

    unsigned char* ws = (unsigned char*)d_ws;
    float*          out3  = (float*)(ws + OUT3_OFF);
    unsigned short* tpack = (unsigned short*)(ws + TPACK_OFF);
    float*          out   = (float*)d_out;

    dim3 gA(64, 3);
    mlp_kernel<<<gA, 256, 0, stream>>>(latents, Win, b_in, Wh, b_h, Wout, b_out, out3);
    tpack_init<<<128, 256, 0, stream>>>(tpack);
    synth_row<<<1024, 512, 0, stream>>>(out3, phase0_u, noise_u, tpack, out);
}

// Round 6
// 469.472 us; speedup vs baseline: 1.5083x; 1.1574x over previous
//
#include <hip/hip_runtime.h>
#include <hip/hip_bf16.h>

#define PI_F 3.14159265358979323846f

typedef short  bf16x8 __attribute__((ext_vector_type(8)));
typedef unsigned short u16x8 __attribute__((ext_vector_type(8)));
typedef float  f32x4  __attribute__((ext_vector_type(4)));

// ---- ws layout (bytes) ----
#define OUT3_OFF  0                       // [3][1024][257] f32 = 3,158,016 B
#define TPACK_OFF 3158016                 // [512 tiles][64][8] bf16 = 524,288 B

#define RPB 8                             // rows per block in mlp_kernel

static __device__ __forceinline__ unsigned short f2bf(float x) {
    unsigned int u = __float_as_uint(x);
    unsigned int r = (u + 0x7fffu + ((u >> 16) & 1u)) >> 16;   // RNE
    return (unsigned short)r;
}

// ------------------------------------------------------------------
// Kernel A: three LinearOutputStacks. 8 rows/block, grid (128,3).
// float4 LDS activation reads + 16-deep weight prefetch.
// ------------------------------------------------------------------

__device__ __forceinline__ void block_ln8(float (*buf)[256], float* mrow, float* rrow)
{
    const int tid = threadIdx.x;
    const int lane = tid & 63, wv = tid >> 6;
    for (int r = wv; r < RPB; r += 4) {
        float s = 0.f, s2 = 0.f;
        #pragma unroll
        for (int j = 0; j < 4; j++) {
            float v = buf[r][lane + 64*j];
            s += v; s2 += v*v;
        }
        #pragma unroll
        for (int o = 32; o > 0; o >>= 1) {
            s  += __shfl_xor(s,  o, 64);
            s2 += __shfl_xor(s2, o, 64);
        }
        if (lane == 0) {
            float m   = s * (1.f/256.f);
            float var = s2 * (1.f/256.f) - m*m;
            mrow[r] = m;
            rrow[r] = rsqrtf(var + 1e-5f);
        }
    }
    __syncthreads();
    #pragma unroll
    for (int r = 0; r < RPB; r++)
        buf[r][tid] = (buf[r][tid] - mrow[r]) * rrow[r];
    __syncthreads();
}

// KDIM -> 256 matmul + bias + leaky_relu(0.2)
template<int KDIM>
__device__ __forceinline__ void mmv(const float (*in)[KDIM == 128 ? 128 : 256],
                                    const float* __restrict__ W, int wstride,
                                    const float* __restrict__ bias, float (*outb)[256])
{
    const int tid = threadIdx.x;
    float acc[RPB];
    #pragma unroll
    for (int r = 0; r < RPB; r++) acc[r] = 0.f;
    const float* Wp = W + tid;
    for (int l16 = 0; l16 < KDIM; l16 += 16) {
        float wbuf[16];
        #pragma unroll
        for (int j = 0; j < 16; j++) wbuf[j] = Wp[(size_t)(l16 + j)*wstride];
        #pragma unroll
        for (int q = 0; q < 4; q++) {
            f32x4 iq[RPB];
            #pragma unroll
            for (int r = 0; r < RPB; r++) iq[r] = *(const f32x4*)&in[r][l16 + q*4];
            #pragma unroll
            for (int jj = 0; jj < 4; jj++)
                #pragma unroll
                for (int r = 0; r < RPB; r++)
                    acc[r] = fmaf(iq[r][jj], wbuf[q*4 + jj], acc[r]);
        }
    }
    const float bb = bias[tid];
    #pragma unroll
    for (int r = 0; r < RPB; r++) {
        float v = acc[r] + bb;
        outb[r][tid] = (v >= 0.f) ? v : 0.2f*v;
    }
}

__global__ __launch_bounds__(256) void mlp_kernel(
    const float* __restrict__ latents,
    const float* __restrict__ Win,  const float* __restrict__ b_in,
    const float* __restrict__ Wh,   const float* __restrict__ b_h,
    const float* __restrict__ Wout, const float* __restrict__ b_out,
    float* __restrict__ out3)
{
    __shared__ float bufA[RPB][128];
    __shared__ float bufB[RPB][256];
    __shared__ float bufC[RPB][256];
    __shared__ float mrow[RPB], rrow[RPB];

    const int tid  = threadIdx.x;
    const int s    = blockIdx.y;
    const int row0 = blockIdx.x * RPB;

    for (int idx = tid; idx < RPB*128; idx += 256) {
        int r = idx >> 7, l = idx & 127;
        bufA[r][l] = latents[(size_t)(row0 + r)*128 + l];
    }
    __syncthreads();

    mmv<128>(bufA, Win + (size_t)s*128*256, 256, b_in + s*256, bufB);
    __syncthreads();
    block_ln8(bufB, mrow, rrow);

    mmv<256>(bufB, Wh + ((size_t)s*2 + 0)*256*256, 256, b_h + (s*2 + 0)*256, bufC);
    __syncthreads();
    block_ln8(bufC, mrow, rrow);

    mmv<256>(bufC, Wh + ((size_t)s*2 + 1)*256*256, 256, b_h + (s*2 + 1)*256, bufB);
    __syncthreads();
    block_ln8(bufB, mrow, rrow);

    // output layer: 256 -> 257 (+bias), raw
    for (int pass = 0; pass < 2; ++pass) {
        int n = tid + pass*256;
        if (n < 257) {
            float acc[RPB];
            #pragma unroll
            for (int r = 0; r < RPB; r++) acc[r] = 0.f;
            const float* Wp = Wout + (size_t)s*256*257 + n;
            for (int l16 = 0; l16 < 256; l16 += 16) {
                float wbuf[16];
                #pragma unroll
                for (int j = 0; j < 16; j++) wbuf[j] = Wp[(size_t)(l16 + j)*257];
                #pragma unroll
                for (int q = 0; q < 4; q++) {
                    f32x4 iq[RPB];
                    #pragma unroll
                    for (int r = 0; r < RPB; r++) iq[r] = *(const f32x4*)&bufB[r][l16 + q*4];
                    #pragma unroll
                    for (int jj = 0; jj < 4; jj++)
                        #pragma unroll
                        for (int r = 0; r < RPB; r++)
                            acc[r] = fmaf(iq[r][jj], wbuf[q*4 + jj], acc[r]);
                }
            }
            float bb = b_out[s*257 + n];
            for (int r = 0; r < RPB; r++)
                out3[((size_t)s*1024 + row0 + r)*257 + n] = acc[r] + bb;
        }
    }
}

// ------------------------------------------------------------------
// K1: pack iDFT basis T[k2][w] (bf16), MFMA B-fragment order, K=512.
// ------------------------------------------------------------------
__global__ __launch_bounds__(256) void tpack_init(unsigned short* __restrict__ tp)
{
    int g = blockIdx.x * 256 + threadIdx.x;      // 512*64 = 32768 threads exactly
    int tile = g >> 6, l = g & 63;
    int ks = tile >> 5, nt = tile & 31;
    u16x8 v;
    #pragma unroll
    for (int j = 0; j < 8; ++j) {
        int k2 = ks*32 + ((l >> 4) << 3) + j;    // < 512
        int w  = nt*16 + (l & 15);
        int kk = k2 >> 1;
        int m  = (kk * w) & 511;                 // exact angle reduction
        float ang = (float)m * (PI_F / 256.f);
        float sn, cn; sincosf(ang, &sn, &cn);
        v[j] = f2bf((k2 & 1) ? sn : cn);
    }
    *(u16x8*)(tp + (size_t)g * 8) = v;
}

// ------------------------------------------------------------------
// K2: full-row fused scan + MFMA iDFT + Hann/OLA.
// grid 1024, block 512 (8 waves), 2 blocks/CU.
// Streaming data (noise in, out) uses NON-TEMPORAL accesses so L2 stays
// dedicated to tpack (512 KB, read by every block every sweep).
// ------------------------------------------------------------------
__global__ __launch_bounds__(512, 4) void synth_row(
    const float* __restrict__ out3,
    const float* __restrict__ phase0_u,
    const float* __restrict__ noise_u,
    const unsigned short* __restrict__ tpack,
    float* __restrict__ out)
{
    __shared__ __align__(16) unsigned char lds_raw[66560];
    __shared__ float a256s[64];
    unsigned int* abt = (unsigned int*)lds_raw;     // [64][260] u32
    float*        xbf = (float*)lds_raw;            // [32][516] f32

    const int tid = threadIdx.x;
    const int row = blockIdx.x;
    const int b   = row >> 9;
    const int e   = row & 511;

    // ---- per-thread sequential state (k = tid, 0..256), in revolutions ----
    const float inv = 0.04419417382415922f;         // 1/sqrt(512)
    float res = 0.f, dith = 0.f, pr = 0.f, mag = 0.f, gd = 0.f, cs = 0.f;
    if (tid <= 256) {
        const int k = tid;
        float ini  = out3[((size_t)0*1024 + row)*257 + k];
        float rpre = out3[((size_t)1*1024 + row)*257 + k];
        float dpre = out3[((size_t)2*1024 + row)*257 + k];
        res  = 0.5f + 0.4995f / (1.f + expf(-rpre));
        dith = 1.f / (1.f + expf(-dpre));
        pr   = phase0_u[(size_t)row*257 + k] - 0.5f;      // rev
        mag  = ini;
        gd   = (float)k * (1.f/512.f);                     // rev per frame
        cs   = ((k == 0) | (k == 256) ? 1.f : 2.f) * inv;
    }

    const float* nrow = noise_u + ((size_t)b*128*512 + e)*257;
    const size_t nstride = (size_t)512*257;

    // OLA constants for w = tid (threads < 256)
    float h1 = 0.f, h2 = 0.f;
    {
        float c0 = cosf((float)tid * (PI_F/256.f));
        h1 = 0.5f - 0.5f*c0;                        // hann[tid]
        h2 = 0.5f + 0.5f*c0;                        // hann[tid+256]
    }
    float tail = 0.f;

    const int l  = tid & 63;
    const int wv = tid >> 6;                        // 0..7: 64-col slice
    const int m0 = l & 15;
    const int ac = l >> 4;
    const int4* abt4 = (const int4*)lds_raw;        // row stride 65 int4
    const int4* Tp   = (const int4*)tpack;

    for (int sweep = 0; sweep < 2; ++sweep) {
        const int F0 = sweep * 64;

        // ---- phase 1: scan 64 frames -> abt (+ a256s) ----
        if (tid <= 256) {
            const int k = tid;
            #pragma unroll
            for (int grp = 0; grp < 4; ++grp) {
                float nzb[16];
                #pragma unroll
                for (int j = 0; j < 16; ++j) {
                    int t = F0 + grp*16 + j;
                    nzb[j] = (t >= 1) ? __builtin_nontemporal_load(
                                            &nrow[(size_t)t*nstride + k]) : 0.5f;
                }
                #pragma unroll
                for (int j = 0; j < 16; ++j) {
                    int t = F0 + grp*16 + j;
                    if (t >= 1) {
                        mag *= res;
                        pr  += gd + dith * (nzb[j] - 0.5f);
                    }
                    float fr = pr - floorf(pr);
                    float sn = __builtin_amdgcn_sinf(fr);
                    float cn = __builtin_amdgcn_cosf(fr);
                    float am = cs * mag;
                    if (k < 256) {
                        abt[(grp*16 + j)*260 + k] =
                            (unsigned int)f2bf(am*cn) | ((unsigned int)f2bf(-am*sn) << 16);
                    } else {
                        a256s[grp*16 + j] = am * cn;   // sin(pi*w)=0: only cos term
                    }
                }
            }
        }
        __syncthreads();

        // ---- phase 2: MFMA  X[f][w] = AB^T[f][k2] * T[k2][w], M=64, K=512 ----
        f32x4 acc[4][4];
        #pragma unroll
        for (int mt = 0; mt < 4; ++mt)
            #pragma unroll
            for (int nt = 0; nt < 4; ++nt)
                acc[mt][nt] = (f32x4){0.f, 0.f, 0.f, 0.f};

        for (int ks = 0; ks < 16; ++ks) {
            int4 ai[4];
            #pragma unroll
            for (int mt = 0; mt < 4; ++mt)
                ai[mt] = abt4[(m0 + 16*mt)*65 + ks*4 + ac];
            const int4* tb = Tp + (size_t)(ks*32 + wv*4)*64 + l;
            #pragma unroll
            for (int nt = 0; nt < 4; ++nt) {
                int4 bi = tb[nt*64];
                bf16x8 B = *(bf16x8*)&bi;
                #pragma unroll
                for (int mt = 0; mt < 4; ++mt) {
                    bf16x8 A = *(bf16x8*)&ai[mt];
                    acc[mt][nt] = __builtin_amdgcn_mfma_f32_16x16x32_bf16(A, B, acc[mt][nt], 0, 0, 0);
                }
            }
        }
        __syncthreads();   // abt reads done; xbf may overwrite

        // ---- phase 3: two 32-frame halves: acc -> xb -> Hann+OLA ----
        #pragma unroll
        for (int h = 0; h < 2; ++h) {
            #pragma unroll
            for (int mt2 = 0; mt2 < 2; ++mt2) {
                int mtg = 2*h + mt2;
                #pragma unroll
                for (int nt = 0; nt < 4; ++nt) {
                    int col = (wv*4 + nt)*16 + m0;
                    #pragma unroll
                    for (int r = 0; r < 4; ++r) {
                        int f_loc = mt2*16 + ac*4 + r;
                        xbf[f_loc*516 + col] = acc[mtg][nt][r];
                    }
                }
            }
            __syncthreads();
            if (tid < 256) {
                float sgn = (tid & 1) ? -1.f : 1.f;
                float* orow = out + (size_t)row*32768 + (size_t)(F0 + h*32)*256 + tid;
                #pragma unroll
                for (int f = 0; f < 32; ++f) {
                    float s  = a256s[h*32 + f] * sgn;
                    float x1 = xbf[f*516 + tid] + s;
                    float x2 = xbf[f*516 + tid + 256] + s;
                    float v  = fmaf(x1, h1, tail);
                    tail = x2 * h2;
                    __builtin_nontemporal_store(v, &orow[f*256]);
                }
            }
            __syncthreads();   // xb reads done before next write / next sweep's abt
        }
    }
}

// ------------------------------------------------------------------

extern "C" void kernel_launch(void* const* d_in, const int* in_sizes, int n_in,
                              void* d_out, int out_size, void* d_ws, size_t ws_size,
                              hipStream_t stream)
{
    const float* latents  = (const float*)d_in[0];
    const float* phase0_u = (const float*)d_in[1];
    const float* noise_u  = (const float*)d_in[2];
    const float* Win      = (const float*)d_in[3];
    const float* b_in     = (const float*)d_in[4];
    const float* Wh       = (const float*)d_in[5];
    const float* b_h      = (const float*)d_in[6];
    const float* Wout     = (const float*)d_in[7];
    const float* b_out    = (const float*)d_in[8];

    unsigned char* ws = (unsigned char*)d_ws;
    float*          out3  = (float*)(ws + OUT3_OFF);
    unsigned short* tpack = (unsigned short*)(ws + TPACK_OFF);
    float*          out   = (float*)d_out;

    dim3 gA(128, 3);
    mlp_kernel<<<gA, 256, 0, stream>>>(latents, Win, b_in, Wh, b_h, Wout, b_out, out3);
    tpack_init<<<128, 256, 0, stream>>>(tpack);
    synth_row<<<1024, 512, 0, stream>>>(out3, phase0_u, noise_u, tpack, out);
}

// Round 7
// 272.558 us; speedup vs baseline: 2.5980x; 1.7225x over previous
//
#include <hip/hip_runtime.h>
#include <hip/hip_bf16.h>

#define PI_F 3.14159265358979323846f

typedef short  bf16x8 __attribute__((ext_vector_type(8)));
typedef unsigned short u16x8 __attribute__((ext_vector_type(8)));
typedef float  f32x4  __attribute__((ext_vector_type(4)));

// ---- ws layout (bytes) ----
#define OUT3_OFF  0                       // [3][1024][257] f32 = 3,158,016 B
#define TPACK_OFF 3158016                 // [256 tiles][64][8] bf16 = 262,144 B

#define RPB 8                             // rows per block in mlp_kernel

static __device__ __forceinline__ unsigned short f2bf(float x) {
    unsigned int u = __float_as_uint(x);
    unsigned int r = (u + 0x7fffu + ((u >> 16) & 1u)) >> 16;   // RNE
    return (unsigned short)r;
}

// ------------------------------------------------------------------
// Kernel A: three LinearOutputStacks. 8 rows/block, grid (128,3).
// ------------------------------------------------------------------

__device__ __forceinline__ void block_ln8(float (*buf)[256], float* mrow, float* rrow)
{
    const int tid = threadIdx.x;
    const int lane = tid & 63, wv = tid >> 6;
    for (int r = wv; r < RPB; r += 4) {
        float s = 0.f, s2 = 0.f;
        #pragma unroll
        for (int j = 0; j < 4; j++) {
            float v = buf[r][lane + 64*j];
            s += v; s2 += v*v;
        }
        #pragma unroll
        for (int o = 32; o > 0; o >>= 1) {
            s  += __shfl_xor(s,  o, 64);
            s2 += __shfl_xor(s2, o, 64);
        }
        if (lane == 0) {
            float m   = s * (1.f/256.f);
            float var = s2 * (1.f/256.f) - m*m;
            mrow[r] = m;
            rrow[r] = rsqrtf(var + 1e-5f);
        }
    }
    __syncthreads();
    #pragma unroll
    for (int r = 0; r < RPB; r++)
        buf[r][tid] = (buf[r][tid] - mrow[r]) * rrow[r];
    __syncthreads();
}

// KDIM -> 256 matmul + bias + leaky_relu(0.2)
template<int KDIM>
__device__ __forceinline__ void mmv(const float (*in)[KDIM == 128 ? 128 : 256],
                                    const float* __restrict__ W, int wstride,
                                    const float* __restrict__ bias, float (*outb)[256])
{
    const int tid = threadIdx.x;
    float acc[RPB];
    #pragma unroll
    for (int r = 0; r < RPB; r++) acc[r] = 0.f;
    const float* Wp = W + tid;
    for (int l16 = 0; l16 < KDIM; l16 += 16) {
        float wbuf[16];
        #pragma unroll
        for (int j = 0; j < 16; j++) wbuf[j] = Wp[(size_t)(l16 + j)*wstride];
        #pragma unroll
        for (int q = 0; q < 4; q++) {
            f32x4 iq[RPB];
            #pragma unroll
            for (int r = 0; r < RPB; r++) iq[r] = *(const f32x4*)&in[r][l16 + q*4];
            #pragma unroll
            for (int jj = 0; jj < 4; jj++)
                #pragma unroll
                for (int r = 0; r < RPB; r++)
                    acc[r] = fmaf(iq[r][jj], wbuf[q*4 + jj], acc[r]);
        }
    }
    const float bb = bias[tid];
    #pragma unroll
    for (int r = 0; r < RPB; r++) {
        float v = acc[r] + bb;
        outb[r][tid] = (v >= 0.f) ? v : 0.2f*v;
    }
}

__global__ __launch_bounds__(256) void mlp_kernel(
    const float* __restrict__ latents,
    const float* __restrict__ Win,  const float* __restrict__ b_in,
    const float* __restrict__ Wh,   const float* __restrict__ b_h,
    const float* __restrict__ Wout, const float* __restrict__ b_out,
    float* __restrict__ out3)
{
    __shared__ float bufA[RPB][128];
    __shared__ float bufB[RPB][256];
    __shared__ float bufC[RPB][256];
    __shared__ float mrow[RPB], rrow[RPB];

    const int tid  = threadIdx.x;
    const int s    = blockIdx.y;
    const int row0 = blockIdx.x * RPB;

    for (int idx = tid; idx < RPB*128; idx += 256) {
        int r = idx >> 7, l = idx & 127;
        bufA[r][l] = latents[(size_t)(row0 + r)*128 + l];
    }
    __syncthreads();

    mmv<128>(bufA, Win + (size_t)s*128*256, 256, b_in + s*256, bufB);
    __syncthreads();
    block_ln8(bufB, mrow, rrow);

    mmv<256>(bufB, Wh + ((size_t)s*2 + 0)*256*256, 256, b_h + (s*2 + 0)*256, bufC);
    __syncthreads();
    block_ln8(bufC, mrow, rrow);

    mmv<256>(bufC, Wh + ((size_t)s*2 + 1)*256*256, 256, b_h + (s*2 + 1)*256, bufB);
    __syncthreads();
    block_ln8(bufB, mrow, rrow);

    // output layer: 256 -> 257 (+bias), raw
    for (int pass = 0; pass < 2; ++pass) {
        int n = tid + pass*256;
        if (n < 257) {
            float acc[RPB];
            #pragma unroll
            for (int r = 0; r < RPB; r++) acc[r] = 0.f;
            const float* Wp = Wout + (size_t)s*256*257 + n;
            for (int l16 = 0; l16 < 256; l16 += 16) {
                float wbuf[16];
                #pragma unroll
                for (int j = 0; j < 16; j++) wbuf[j] = Wp[(size_t)(l16 + j)*257];
                #pragma unroll
                for (int q = 0; q < 4; q++) {
                    f32x4 iq[RPB];
                    #pragma unroll
                    for (int r = 0; r < RPB; r++) iq[r] = *(const f32x4*)&bufB[r][l16 + q*4];
                    #pragma unroll
                    for (int jj = 0; jj < 4; jj++)
                        #pragma unroll
                        for (int r = 0; r < RPB; r++)
                            acc[r] = fmaf(iq[r][jj], wbuf[q*4 + jj], acc[r]);
                }
            }
            float bb = b_out[s*257 + n];
            for (int r = 0; r < RPB; r++)
                out3[((size_t)s*1024 + row0 + r)*257 + n] = acc[r] + bb;
        }
    }
}

// ------------------------------------------------------------------
// K1: pack iDFT basis T[k2][w] (bf16), MFMA B-fragment order.
// Only w = 0..255 columns (w-symmetry handled in GEMM): 256 tiles.
//  tile = ks*16 + nt;  k2 = ks*32 + (l>>4)*8 + j (cos/sin interleaved),
//  w = nt*16 + (l&15).
// ------------------------------------------------------------------
__global__ __launch_bounds__(256) void tpack_init(unsigned short* __restrict__ tp)
{
    int g = blockIdx.x * 256 + threadIdx.x;      // 256*64 = 16384 threads exactly
    int tile = g >> 6, l = g & 63;
    int ks = tile >> 4, nt = tile & 15;
    u16x8 v;
    #pragma unroll
    for (int j = 0; j < 8; ++j) {
        int k2 = ks*32 + ((l >> 4) << 3) + j;    // < 512
        int w  = nt*16 + (l & 15);               // < 256
        int kk = k2 >> 1;
        int m  = (kk * w) & 511;                 // exact angle reduction
        float ang = (float)m * (PI_F / 256.f);
        float sn, cn; sincosf(ang, &sn, &cn);
        v[j] = f2bf((k2 & 1) ? sn : cn);
    }
    *(u16x8*)(tp + (size_t)g * 8) = v;
}

// ------------------------------------------------------------------
// K2: full-row fused scan + MFMA iDFT + Hann/OLA.
// grid 1024, block 512 (8 waves), 2 blocks/CU (128-reg budget, no spills).
// GEMM computes only w=0..255 (N=256, K=512); w+256 columns come from the
// sign-flipped A operand: x[w+256] = sum_k (-1)^k (a_k cos + b_k sin),
// where (-1)^k flips fragment words 1,3 (XOR 0x80008000) -- 2 VALU ops.
// Wave wv owns cols [wv*32, wv*32+32) (and +256 via accR).
// LDS union: abt u32[64][260] (scan/GEMM)  |  xbf f32[32][516] (epilogue)
// ------------------------------------------------------------------
__global__ __launch_bounds__(512, 4) void synth_row(
    const float* __restrict__ out3,
    const float* __restrict__ phase0_u,
    const float* __restrict__ noise_u,
    const unsigned short* __restrict__ tpack,
    float* __restrict__ out)
{
    __shared__ __align__(16) unsigned char lds_raw[66560];
    __shared__ float a256s[64];
    unsigned int* abt = (unsigned int*)lds_raw;     // [64][260] u32
    float*        xbf = (float*)lds_raw;            // [32][516] f32

    const int tid = threadIdx.x;
    const int row = blockIdx.x;
    const int b   = row >> 9;
    const int e   = row & 511;

    // ---- per-thread sequential state (k = tid, 0..256), in revolutions ----
    const float inv = 0.04419417382415922f;         // 1/sqrt(512)
    float res = 0.f, dith = 0.f, pr = 0.f, mag = 0.f, gd = 0.f, cs = 0.f;
    if (tid <= 256) {
        const int k = tid;
        float ini  = out3[((size_t)0*1024 + row)*257 + k];
        float rpre = out3[((size_t)1*1024 + row)*257 + k];
        float dpre = out3[((size_t)2*1024 + row)*257 + k];
        res  = 0.5f + 0.4995f / (1.f + expf(-rpre));
        dith = 1.f / (1.f + expf(-dpre));
        pr   = phase0_u[(size_t)row*257 + k] - 0.5f;      // rev
        mag  = ini;
        gd   = (float)k * (1.f/512.f);                     // rev per frame
        cs   = ((k == 0) | (k == 256) ? 1.f : 2.f) * inv;
    }

    const float* nrow = noise_u + ((size_t)b*128*512 + e)*257;
    const size_t nstride = (size_t)512*257;

    float tail = 0.f;

    const int l  = tid & 63;
    const int wv = tid >> 6;                        // 0..7: 32-col slice
    const int m0 = l & 15;
    const int ac = l >> 4;
    const int4* abt4 = (const int4*)lds_raw;        // row stride 65 int4
    const int4* Tp   = (const int4*)tpack;

    for (int sweep = 0; sweep < 2; ++sweep) {
        const int F0 = sweep * 64;

        // ---- phase 1: scan 64 frames -> abt (+ a256s) ----
        if (tid <= 256) {
            const int k = tid;
            for (int grp = 0; grp < 8; ++grp) {
                float nzb[8];
                #pragma unroll
                for (int j = 0; j < 8; ++j) {
                    int t = F0 + grp*8 + j;
                    nzb[j] = (t >= 1) ? __builtin_nontemporal_load(
                                            &nrow[(size_t)t*nstride + k]) : 0.5f;
                }
                #pragma unroll
                for (int j = 0; j < 8; ++j) {
                    int t = F0 + grp*8 + j;
                    if (t >= 1) {
                        mag *= res;
                        pr  += gd + dith * (nzb[j] - 0.5f);
                    }
                    float fr = pr - floorf(pr);
                    float sn = __builtin_amdgcn_sinf(fr);
                    float cn = __builtin_amdgcn_cosf(fr);
                    float am = cs * mag;
                    if (k < 256) {
                        abt[(grp*8 + j)*260 + k] =
                            (unsigned int)f2bf(am*cn) | ((unsigned int)f2bf(-am*sn) << 16);
                    } else {
                        a256s[grp*8 + j] = am * cn;   // sin(pi*w)=0: only cos term
                    }
                }
            }
        }
        __syncthreads();

        // ---- phase 2: MFMA  M=64 (frames), N=256 (w), K=512; dual-sign acc ----
        f32x4 accL[4][2], accR[4][2];
        #pragma unroll
        for (int mt = 0; mt < 4; ++mt)
            #pragma unroll
            for (int nt = 0; nt < 2; ++nt) {
                accL[mt][nt] = (f32x4){0.f, 0.f, 0.f, 0.f};
                accR[mt][nt] = (f32x4){0.f, 0.f, 0.f, 0.f};
            }

        for (int ks = 0; ks < 16; ++ks) {
            const int4* tb = Tp + (size_t)(ks*16 + wv*2)*64 + l;
            int4 b0 = tb[0];
            int4 b1 = tb[64];
            bf16x8 B0 = *(bf16x8*)&b0;
            bf16x8 B1 = *(bf16x8*)&b1;
            #pragma unroll
            for (int mt = 0; mt < 4; ++mt) {
                int4 a = abt4[(m0 + 16*mt)*65 + ks*4 + ac];
                bf16x8 A = *(bf16x8*)&a;
                accL[mt][0] = __builtin_amdgcn_mfma_f32_16x16x32_bf16(A, B0, accL[mt][0], 0, 0, 0);
                accL[mt][1] = __builtin_amdgcn_mfma_f32_16x16x32_bf16(A, B1, accL[mt][1], 0, 0, 0);
                int4 a2 = a;
                a2.y ^= 0x80008000;               // flip sign where k odd
                a2.w ^= 0x80008000;
                bf16x8 A2 = *(bf16x8*)&a2;
                accR[mt][0] = __builtin_amdgcn_mfma_f32_16x16x32_bf16(A2, B0, accR[mt][0], 0, 0, 0);
                accR[mt][1] = __builtin_amdgcn_mfma_f32_16x16x32_bf16(A2, B1, accR[mt][1], 0, 0, 0);
            }
        }
        __syncthreads();   // abt reads done; xbf may overwrite

        // ---- phase 3: two 32-frame halves: acc -> xbf -> Hann+OLA ----
        #pragma unroll
        for (int h = 0; h < 2; ++h) {
            #pragma unroll
            for (int mt2 = 0; mt2 < 2; ++mt2) {
                int mtg = 2*h + mt2;
                #pragma unroll
                for (int nt = 0; nt < 2; ++nt) {
                    int colL = wv*32 + nt*16 + m0;
                    #pragma unroll
                    for (int r = 0; r < 4; ++r) {
                        int f_loc = mt2*16 + ac*4 + r;
                        xbf[f_loc*516 + colL      ] = accL[mtg][nt][r];
                        xbf[f_loc*516 + colL + 256] = accR[mtg][nt][r];
                    }
                }
            }
            __syncthreads();
            if (tid < 256) {
                float c0 = __builtin_amdgcn_cosf((float)tid * (1.f/512.f));
                float h1 = 0.5f - 0.5f*c0;          // hann[tid]
                float h2 = 0.5f + 0.5f*c0;          // hann[tid+256]
                float sgn = (tid & 1) ? -1.f : 1.f;
                float* orow = out + (size_t)row*32768 + (size_t)(F0 + h*32)*256 + tid;
                #pragma unroll
                for (int f = 0; f < 32; ++f) {
                    float s  = a256s[h*32 + f] * sgn;
                    float x1 = xbf[f*516 + tid] + s;
                    float x2 = xbf[f*516 + tid + 256] + s;
                    float v  = fmaf(x1, h1, tail);
                    tail = x2 * h2;
                    __builtin_nontemporal_store(v, &orow[f*256]);
                }
            }
            __syncthreads();   // xbf reads done before next write / next abt
        }
    }
}

// ------------------------------------------------------------------

extern "C" void kernel_launch(void* const* d_in, const int* in_sizes, int n_in,
                              void* d_out, int out_size, void* d_ws, size_t ws_size,
                              hipStream_t stream)
{
    const float* latents  = (const float*)d_in[0];
    const float* phase0_u = (const float*)d_in[1];
    const float* noise_u  = (const float*)d_in[2];
    const float* Win      = (const float*)d_in[3];
    const float* b_in     = (const float*)d_in[4];
    const float* Wh       = (const float*)d_in[5];
    const float* b_h      = (const float*)d_in[6];
    const float* Wout     = (const float*)d_in[7];
    const float* b_out    = (const float*)d_in[8];

    unsigned char* ws = (unsigned char*)d_ws;
    float*          out3  = (float*)(ws + OUT3_OFF);
    unsigned short* tpack = (unsigned short*)(ws + TPACK_OFF);
    float*          out   = (float*)d_out;

    dim3 gA(128, 3);
    mlp_kernel<<<gA, 256, 0, stream>>>(latents, Win, b_in, Wh, b_h, Wout, b_out, out3);
    tpack_init<<<64, 256, 0, stream>>>(tpack);
    synth_row<<<1024, 512, 0, stream>>>(out3, phase0_u, noise_u, tpack, out);
}